// Round 1
// baseline (7958.783 us; speedup 1.0000x reference)
//
#include <hip/hip_runtime.h>
#include <math.h>

#define B 64
#define N 1024
#define D 256
#define H 256
#define G3 768            // 3*H
#define NUM_BAGS (B*N)

__device__ __forceinline__ float sigmoidf_(float x) { return 1.0f / (1.0f + expf(-x)); }

// ---------------------------------------------------------------------------
// Kernel 1: transpose w_ih [768,256] -> w_ihT [256,768], same for w_hh.
// ---------------------------------------------------------------------------
__global__ void k_transpose(const float* __restrict__ w_ih, const float* __restrict__ w_hh,
                            float* __restrict__ w_ihT, float* __restrict__ w_hhT) {
    int idx = blockIdx.x * blockDim.x + threadIdx.x;
    if (idx < G3 * D) {
        int j = idx / D;       // gate row 0..767
        int d = idx % D;       // input dim
        w_ihT[d * G3 + j] = w_ih[idx];
        w_hhT[d * G3 + j] = w_hh[idx];
    }
}

// ---------------------------------------------------------------------------
// Kernel 2: TE2 = type_emb @ w_ihT  (300x768),  PE2 = pos_table @ w_ihT (1000x768)
// One block per table row; thread k computes gate cols {k, k+256, k+512}.
// ---------------------------------------------------------------------------
__global__ void k_table_gemm(const float* __restrict__ type_emb, const float* __restrict__ pos_table,
                             const float* __restrict__ w_ihT,
                             float* __restrict__ TE2, float* __restrict__ PE2) {
    __shared__ float row[D];
    int r = blockIdx.x;
    const float* src;
    float* dst;
    if (r < 300) { src = type_emb + (size_t)r * D;        dst = TE2 + (size_t)r * G3; }
    else         { src = pos_table + (size_t)(r - 300) * D; dst = PE2 + (size_t)(r - 300) * G3; }
    int k = threadIdx.x;
    row[k] = src[k];
    __syncthreads();
    float a0 = 0.f, a1 = 0.f, a2 = 0.f;
#pragma unroll 8
    for (int d = 0; d < D; ++d) {
        float p = row[d];
        const float* w = w_ihT + d * G3;
        a0 += p * w[k];
        a1 += p * w[k + 256];
        a2 += p * w[k + 512];
    }
    dst[k] = a0; dst[k + 256] = a1; dst[k + 512] = a2;
}

// ---------------------------------------------------------------------------
// Kernel 3: output columns [0, D):
//   out[i,b,0:D] = 4*type_emb[t] + 0.25*pos_table[c] + 4*mean(token_emb[vals in bag])
// 4 bags per 256-thread block, float4 per lane (64 lanes per bag).
// ---------------------------------------------------------------------------
__global__ void k_embed_out(const int* __restrict__ node_types, const int* __restrict__ child_pos,
                            const int* __restrict__ node_vals, const int* __restrict__ offsets,
                            const float* __restrict__ type_emb, const float* __restrict__ pos_table,
                            const float* __restrict__ token_emb, float* __restrict__ out, int Ltot) {
    int tid = threadIdx.x;
    int bag = blockIdx.x * 4 + (tid >> 6);
    int q   = (tid & 63) * 4;            // float offset within row
    int b = bag >> 10;                   // bag = b*N + i, N = 1024
    int i = bag & 1023;
    int t = node_types[bag];
    int c = child_pos[bag];
    int start = offsets[bag];
    int end   = (bag + 1 < NUM_BAGS) ? offsets[bag + 1] : Ltot;

    float4 s = make_float4(0.f, 0.f, 0.f, 0.f);
    for (int l = start; l < end; ++l) {
        float4 v = *(const float4*)(token_emb + (size_t)node_vals[l] * D + q);
        s.x += v.x; s.y += v.y; s.z += v.z; s.w += v.w;
    }
    int cnt = end - start; if (cnt < 1) cnt = 1;
    float inv = 4.0f / (float)cnt;       // SCALE * mean
    float4 a = *(const float4*)(type_emb + (size_t)t * D + q);
    float4 p = *(const float4*)(pos_table + (size_t)c * D + q);
    float4 r;
    r.x = 4.f * a.x + 0.25f * p.x + inv * s.x;
    r.y = 4.f * a.y + 0.25f * p.y + inv * s.y;
    r.z = 4.f * a.z + 0.25f * p.z + inv * s.z;
    r.w = 4.f * a.w + 0.25f * p.w + inv * s.w;
    *(float4*)(out + ((size_t)i * B + b) * (D + H) + q) = r;
}

// ---------------------------------------------------------------------------
// Kernel 4: sequential GRU. One block per batch element. Thread k owns hidden
// unit k (gate rows k, k+256, k+512). Hidden history lives directly in d_out
// at out[i,b,D + k] — thread k both writes and reads element k, so the global
// history round-trip is same-thread coherent; only sPrev needs barriers.
// ---------------------------------------------------------------------------
__global__ void __launch_bounds__(256, 1) k_gru(
        const int* __restrict__ node_types, const int* __restrict__ child_pos,
        const int* __restrict__ last_parent,
        const float* __restrict__ TE2, const float* __restrict__ PE2,
        const float* __restrict__ w_hhT,
        const float* __restrict__ b_ih, const float* __restrict__ b_hh,
        float* __restrict__ out) {
    __shared__ float sPrev[H];
    int b = blockIdx.x;
    int k = threadIdx.x;

    float bir = b_ih[k], biz = b_ih[k + 256], bin = b_ih[k + 512];
    float bhr = b_hh[k], bhz = b_hh[k + 256], bhn = b_hh[k + 512];

    const int* nt = node_types  + (size_t)b * N;
    const int* cp = child_pos   + (size_t)b * N;
    const int* lp = last_parent + (size_t)b * N;

    for (int i = 0; i < N; ++i) {
        int lpi = lp[i];
        float pv = 0.f;
        if (i > 0) pv = out[((size_t)lpi * B + b) * (D + H) + D + k];  // same-thread RAW
        __syncthreads();                 // protect sPrev from previous iteration's readers
        sPrev[k] = pv;
        __syncthreads();

        int t = nt[i], c = cp[i];
        const float* te = TE2 + (size_t)t * G3;
        const float* pe = PE2 + (size_t)c * G3;
        float gir = 4.f * te[k]       + 0.25f * pe[k]       + bir;
        float giz = 4.f * te[k + 256] + 0.25f * pe[k + 256] + biz;
        float gin = 4.f * te[k + 512] + 0.25f * pe[k + 512] + bin;

        float ar = bhr, az = bhz, an = bhn;
#pragma unroll 8
        for (int d = 0; d < D; ++d) {
            float p = sPrev[d];
            const float* w = w_hhT + d * G3;
            ar += p * w[k];
            az += p * w[k + 256];
            an += p * w[k + 512];
        }

        float r = sigmoidf_(gir + ar);
        float z = sigmoidf_(giz + az);
        float n = tanhf(gin + r * an);
        float h = (1.f - z) * n + z * pv;
        out[((size_t)i * B + b) * (D + H) + D + k] = h;
    }
}

// ---------------------------------------------------------------------------
extern "C" void kernel_launch(void* const* d_in, const int* in_sizes, int n_in,
                              void* d_out, int out_size, void* d_ws, size_t ws_size,
                              hipStream_t stream) {
    const int*   node_types  = (const int*)d_in[0];
    const int*   node_vals   = (const int*)d_in[1];
    const int*   offsets     = (const int*)d_in[2];
    const int*   last_parent = (const int*)d_in[3];
    const int*   child_pos   = (const int*)d_in[4];
    const float* type_emb    = (const float*)d_in[5];
    const float* pos_table   = (const float*)d_in[6];
    const float* token_emb   = (const float*)d_in[7];
    const float* w_ih        = (const float*)d_in[8];
    const float* w_hh        = (const float*)d_in[9];
    const float* b_ih        = (const float*)d_in[10];
    const float* b_hh        = (const float*)d_in[11];
    float* out = (float*)d_out;

    // Workspace layout (floats): w_ihT | w_hhT | TE2 | PE2  (~5.6 MB total)
    float* ws    = (float*)d_ws;
    float* w_ihT = ws;
    float* w_hhT = w_ihT + (size_t)G3 * D;
    float* TE2   = w_hhT + (size_t)G3 * D;
    float* PE2   = TE2 + (size_t)300 * G3;
    int Ltot = in_sizes[1];

    hipLaunchKernelGGL(k_transpose, dim3((G3 * D + 255) / 256), dim3(256), 0, stream,
                       w_ih, w_hh, w_ihT, w_hhT);
    hipLaunchKernelGGL(k_table_gemm, dim3(1300), dim3(256), 0, stream,
                       type_emb, pos_table, w_ihT, TE2, PE2);
    hipLaunchKernelGGL(k_embed_out, dim3(NUM_BAGS / 4), dim3(256), 0, stream,
                       node_types, child_pos, node_vals, offsets,
                       type_emb, pos_table, token_emb, out, Ltot);
    hipLaunchKernelGGL(k_gru, dim3(B), dim3(256), 0, stream,
                       node_types, child_pos, last_parent, TE2, PE2, w_hhT, b_ih, b_hh, out);
}

// Round 2
// 1850.896 us; speedup vs baseline: 4.3000x; 4.3000x over previous
//
#include <hip/hip_runtime.h>
#include <math.h>

#define B 64
#define N 1024
#define D 256
#define H 256
#define G3 768            // 3*H
#define NUM_BAGS (B*N)
#define OUTW (D+H)

typedef _Float16 h2_t __attribute__((ext_vector_type(2)));
typedef unsigned int uint32;

__device__ __forceinline__ float sigmoidf_(float x) { return 1.0f / (1.0f + expf(-x)); }

__device__ __forceinline__ float dot2f(uint32 a, uint32 b, float c) {
#if __has_builtin(__builtin_amdgcn_fdot2)
    return __builtin_amdgcn_fdot2(__builtin_bit_cast(h2_t, a), __builtin_bit_cast(h2_t, b), c, false);
#else
    h2_t x = __builtin_bit_cast(h2_t, a), y = __builtin_bit_cast(h2_t, b);
    return c + (float)x[0] * (float)y[0] + (float)x[1] * (float)y[1];
#endif
}

// ---------------------------------------------------------------------------
// Kernel 1: w_ihT[d*768+j] = w_ih[j*256+d]  (for k_table_gemm)
//           wpack[m*768+j] = pack_f16(w_hh[j*256+2m], w_hh[j*256+2m+1])
// ---------------------------------------------------------------------------
__global__ void k_prep(const float* __restrict__ w_ih, const float* __restrict__ w_hh,
                       float* __restrict__ w_ihT, uint32* __restrict__ wpack) {
    int idx = blockIdx.x * blockDim.x + threadIdx.x;
    if (idx < G3 * D) {
        int j = idx / D;
        int d = idx % D;
        w_ihT[d * G3 + j] = w_ih[idx];
    }
    if (idx < G3 * 128) {
        int j = idx / 128;
        int m = idx % 128;
        float w0 = w_hh[j * D + 2 * m];
        float w1 = w_hh[j * D + 2 * m + 1];
        h2_t v = { (_Float16)w0, (_Float16)w1 };
        wpack[m * G3 + j] = __builtin_bit_cast(uint32, v);
    }
}

// ---------------------------------------------------------------------------
// Kernel 2: TE2 = type_emb @ w_ihT (300x768), PE2 = pos_table @ w_ihT (1000x768)
// ---------------------------------------------------------------------------
__global__ void k_table_gemm(const float* __restrict__ type_emb, const float* __restrict__ pos_table,
                             const float* __restrict__ w_ihT,
                             float* __restrict__ TE2, float* __restrict__ PE2) {
    __shared__ float row[D];
    int r = blockIdx.x;
    const float* src;
    float* dst;
    if (r < 300) { src = type_emb + (size_t)r * D;          dst = TE2 + (size_t)r * G3; }
    else         { src = pos_table + (size_t)(r - 300) * D; dst = PE2 + (size_t)(r - 300) * G3; }
    int k = threadIdx.x;
    row[k] = src[k];
    __syncthreads();
    float a0 = 0.f, a1 = 0.f, a2 = 0.f;
#pragma unroll 8
    for (int d = 0; d < D; ++d) {
        float p = row[d];
        const float* w = w_ihT + d * G3;
        a0 += p * w[k];
        a1 += p * w[k + 256];
        a2 += p * w[k + 512];
    }
    dst[k] = a0; dst[k + 256] = a1; dst[k + 512] = a2;
}

// ---------------------------------------------------------------------------
// Kernel 3: output columns [0, D)
// ---------------------------------------------------------------------------
__global__ void k_embed_out(const int* __restrict__ node_types, const int* __restrict__ child_pos,
                            const int* __restrict__ node_vals, const int* __restrict__ offsets,
                            const float* __restrict__ type_emb, const float* __restrict__ pos_table,
                            const float* __restrict__ token_emb, float* __restrict__ out, int Ltot) {
    int tid = threadIdx.x;
    int bag = blockIdx.x * 4 + (tid >> 6);
    int q   = (tid & 63) * 4;
    int b = bag >> 10;
    int i = bag & 1023;
    int t = node_types[bag];
    int c = child_pos[bag];
    int start = offsets[bag];
    int end   = (bag + 1 < NUM_BAGS) ? offsets[bag + 1] : Ltot;

    float4 s = make_float4(0.f, 0.f, 0.f, 0.f);
    for (int l = start; l < end; ++l) {
        float4 v = *(const float4*)(token_emb + (size_t)node_vals[l] * D + q);
        s.x += v.x; s.y += v.y; s.z += v.z; s.w += v.w;
    }
    int cnt = end - start; if (cnt < 1) cnt = 1;
    float inv = 4.0f / (float)cnt;
    float4 a = *(const float4*)(type_emb + (size_t)t * D + q);
    float4 p = *(const float4*)(pos_table + (size_t)c * D + q);
    float4 r;
    r.x = 4.f * a.x + 0.25f * p.x + inv * s.x;
    r.y = 4.f * a.y + 0.25f * p.y + inv * s.y;
    r.z = 4.f * a.z + 0.25f * p.z + inv * s.z;
    r.w = 4.f * a.w + 0.25f * p.w + inv * s.w;
    *(float4*)(out + ((size_t)i * B + b) * OUTW + q) = r;
}

// ---------------------------------------------------------------------------
// Kernel 4: sequential GRU, register-resident f16 weights.
// 768 threads/block (12 waves, 3/SIMD), one block per batch.
// Thread j owns gate row j: 128 packed f16x2 weight dwords in VGPRs.
// prev hidden state is broadcast from LDS as f16 pairs (double-buffered).
// Gates exchanged via LDS; threads 0..255 do activations + h write.
// ---------------------------------------------------------------------------
__global__ void __launch_bounds__(768, 3) k_gru(
        const int* __restrict__ node_types, const int* __restrict__ child_pos,
        const int* __restrict__ last_parent,
        const float* __restrict__ TE2, const float* __restrict__ PE2,
        const uint32* __restrict__ wpack,
        const float* __restrict__ b_ih, const float* __restrict__ b_hh,
        float* __restrict__ out) {
    __shared__ __align__(16) _Float16 sprev[2][H];   // packed f16 prev hidden
    __shared__ float gbuf[G3];
    __shared__ float nbuf[H];

    int b = blockIdx.x;
    int j = threadIdx.x;

    // Load this thread's weight row: 128 coalesced dword loads.
    uint32 w[128];
#pragma unroll
    for (int m = 0; m < 128; ++m) w[m] = wpack[m * G3 + j];

    float bi = b_ih[j];
    float bh = b_hh[j];

    const int* nt = node_types  + (size_t)b * N;
    const int* cp = child_pos   + (size_t)b * N;
    const int* lp = last_parent + (size_t)b * N;

    if (j < H) sprev[0][j] = (_Float16)0.f;
    float pv = 0.f;   // parent hidden value for threads < H

    // prefetch gi rows for step 0
    float te = TE2[(size_t)nt[0] * G3 + j];
    float pe = PE2[(size_t)cp[0] * G3 + j];
    __syncthreads();

    for (int i = 0; i < N; ++i) {
        // ---- prefetch for step i+1 (overlaps with the dot) ----
        float te_n = 0.f, pe_n = 0.f, pv_ld = 0.f;
        bool adj = false;
        if (i + 1 < N) {
            te_n = TE2[(size_t)nt[i + 1] * G3 + j];
            pe_n = PE2[(size_t)cp[i + 1] * G3 + j];
        }
        if (j < H && i + 1 < N) {
            int lpn = lp[i + 1];
            adj = (lpn == i);
            if (!adj)   // h[lpn] already written by THIS thread at step lpn
                pv_ld = out[((size_t)lpn * B + b) * OUTW + D + j];
        }

        // ---- dot: gh_j = w_hh[j,:] . prev ----
        const uint32* sp = (const uint32*)sprev[i & 1];
        float a0 = 0.f, a1 = 0.f, a2 = 0.f, a3 = 0.f;
#pragma unroll
        for (int m = 0; m < 128; m += 4) {
            a0 = dot2f(w[m],     sp[m],     a0);
            a1 = dot2f(w[m + 1], sp[m + 1], a1);
            a2 = dot2f(w[m + 2], sp[m + 2], a2);
            a3 = dot2f(w[m + 3], sp[m + 3], a3);
        }
        float gh = (a0 + a1) + (a2 + a3) + bh;
        float gi = 4.f * te + 0.25f * pe + bi;

        if (j < 512) gbuf[j] = gi + gh;   // r,z: pre-activation sum
        else { gbuf[j] = gh; nbuf[j - 512] = gi; }  // n: keep separate (r*hn)
        te = te_n; pe = pe_n;
        __syncthreads();

        // ---- activations + h (threads 0..255) ----
        if (j < H) {
            float r = sigmoidf_(gbuf[j]);
            float z = sigmoidf_(gbuf[H + j]);
            float n = tanhf(nbuf[j] + r * gbuf[2 * H + j]);
            float h = (1.f - z) * n + z * pv;
            out[((size_t)i * B + b) * OUTW + D + j] = h;
            float pvn = adj ? h : pv_ld;
            sprev[(i + 1) & 1][j] = (_Float16)pvn;
            pv = pvn;
        }
        __syncthreads();
    }
}

// ---------------------------------------------------------------------------
extern "C" void kernel_launch(void* const* d_in, const int* in_sizes, int n_in,
                              void* d_out, int out_size, void* d_ws, size_t ws_size,
                              hipStream_t stream) {
    const int*   node_types  = (const int*)d_in[0];
    const int*   node_vals   = (const int*)d_in[1];
    const int*   offsets     = (const int*)d_in[2];
    const int*   last_parent = (const int*)d_in[3];
    const int*   child_pos   = (const int*)d_in[4];
    const float* type_emb    = (const float*)d_in[5];
    const float* pos_table   = (const float*)d_in[6];
    const float* token_emb   = (const float*)d_in[7];
    const float* w_ih        = (const float*)d_in[8];
    const float* w_hh        = (const float*)d_in[9];
    const float* b_ih        = (const float*)d_in[10];
    const float* b_hh        = (const float*)d_in[11];
    float* out = (float*)d_out;

    // Workspace: w_ihT | TE2 | PE2 | wpack  (~5.2 MB)
    float*  ws    = (float*)d_ws;
    float*  w_ihT = ws;
    float*  TE2   = w_ihT + (size_t)G3 * D;
    float*  PE2   = TE2 + (size_t)300 * G3;
    uint32* wpack = (uint32*)(PE2 + (size_t)1000 * G3);
    int Ltot = in_sizes[1];

    hipLaunchKernelGGL(k_prep, dim3((G3 * D + 255) / 256), dim3(256), 0, stream,
                       w_ih, w_hh, w_ihT, wpack);
    hipLaunchKernelGGL(k_table_gemm, dim3(1300), dim3(256), 0, stream,
                       type_emb, pos_table, w_ihT, TE2, PE2);
    hipLaunchKernelGGL(k_embed_out, dim3(NUM_BAGS / 4), dim3(256), 0, stream,
                       node_types, child_pos, node_vals, offsets,
                       type_emb, pos_table, token_emb, out, Ltot);
    hipLaunchKernelGGL(k_gru, dim3(B), dim3(768), 0, stream,
                       node_types, child_pos, last_parent, TE2, PE2, wpack, b_ih, b_hh, out);
}